// Round 12
// baseline (5138.274 us; speedup 1.0000x reference)
//
#include <hip/hip_runtime.h>
#include <hip/hip_bf16.h>

// DeepLSTM on MI355X — v22: two batch groups per block (1024 threads,
// 4 waves/SIMD) to fill the per-step latency bubble.
//
// v21 post-mortem: fire-and-forget stores neutral (806us) — boundary levers
// exhausted. Step accounting: 3000cy with VALU ~41%, MFMA ~27% (overlapped
// pipes) and a ~40% BUBBLE = per-wave latency chains that 2 waves/SIMD
// can't hide. Issue-reduction failed 3x (v15/v16/v19: each added latency).
// The untouched lever is occupancy (Guideline 1): co-residency of separate
// blocks is impossible (224 idle CUs absorb them), so MERGE two groups into
// one 1024-thread block: 16 blocks x 16 waves = 4 waves/SIMD; group-A and
// group-B waves interleave on each SIMD and fill each other's bubbles.
// Weights are identical for both halves (same layer) — no extra VGPR.
// LDS: 2x(xchunk+hist CTT=8) + wout = 159,744 <= 163,840.
// Protocol unchanged: per-(l,g) flags/rings; sub==0 thread of each half
// polls/publishes its own group's flags; upstream publishes both flags at
// its boundary, so lockstep coupling adds no new dependency (no deadlock).
//
// Bet: step stays ~3000-3200cy while doing 2x work -> ~700-760us.
// Failure signature (serial-chain-bound): ~950-1050us -> revert + declare
// structural floor.
//
// Grid: 16 blocks x 1024 threads; block (l,gp) = layer l, group pair gp;
// half gg = tid>>9 handles group g = gp*2+gg (16 rows).
// ws: [0,8KB) flags (prod@0, cons@4KB, 128B stride); [8KB,...) ring
//     [pair][RING_T][16][128] bf16.

#define T_ 512
#define L_ 8
#define H_ 128
#define G4_ 512
#define OUT_ 65
#define B_ 64
#define NG_ 4
#define BG_ 16
#define LDSW_ 136                          // padded LDS row stride (bf16)
#define HT_OFF_ (B_ * T_ * OUT_)           // 2129920
#define CT_OFF_ (HT_OFF_ + L_ * B_ * H_)   // 2195456
#define STEP_U64_ 512                      // one step's h-tile: 16x128 bf16 = 4KB

typedef __bf16 bf16_t;
typedef bf16_t bf16x8 __attribute__((ext_vector_type(8)));
typedef bf16_t bf16x4 __attribute__((ext_vector_type(4)));
typedef float f32x4 __attribute__((ext_vector_type(4)));
typedef unsigned long long u64;

union U128 { uint4 u; bf16x8 b; u64 d[2]; };

__device__ __forceinline__ float rcpf(float x) { return __builtin_amdgcn_rcpf(x); }
__device__ __forceinline__ float sigm(float x) { return rcpf(1.f + __expf(-x)); }
__device__ __forceinline__ float tanh_fast(float x) {
  const float e = __expf(-2.f * fabsf(x));
  const float r = 2.f * rcpf(1.f + e) - 1.f;
  return copysignf(r, x);
}
__device__ __forceinline__ int flag_ld(int* p) {
  return __hip_atomic_load(p, __ATOMIC_RELAXED, __HIP_MEMORY_SCOPE_AGENT);
}
__device__ __forceinline__ void flag_st(int* p, int v) {
  __hip_atomic_store(p, v, __ATOMIC_RELAXED, __HIP_MEMORY_SCOPE_AGENT);
}
__device__ __forceinline__ u64 ring_ld(const u64* p) {
  return __hip_atomic_load(const_cast<u64*>(p), __ATOMIC_RELAXED, __HIP_MEMORY_SCOPE_AGENT);
}
__device__ __forceinline__ void ring_st(u64* p, u64 v) {
  __hip_atomic_store(p, v, __ATOMIC_RELAXED, __HIP_MEMORY_SCOPE_AGENT);
}

// Raw step barrier: order LDS (hist) writes only; leave sc1 ring stores in
// flight across the barrier. sched_barrier(0) per guide rule #18.
#define STEP_BAR()                                                    \
  do {                                                                \
    asm volatile("s_waitcnt lgkmcnt(0)" ::: "memory");                \
    __builtin_amdgcn_sched_barrier(0);                                \
    __builtin_amdgcn_s_barrier();                                     \
  } while (0)

__global__ void zero_flags(int* flags) { flags[blockIdx.x * 1024 + threadIdx.x] = 0; }

template <int SUB, int NSUB, int RING_T>
__global__ __launch_bounds__(1024, 1)
void lstm_pipe(const int* __restrict__ xids, const float* __restrict__ embed,
               const float* __restrict__ wih_g, const float* __restrict__ bih_g,
               const float* __restrict__ whh_g, const float* __restrict__ bhh_g,
               const float* __restrict__ wout_g, const float* __restrict__ bout_g,
               float* __restrict__ out, int* __restrict__ flags,
               u64* __restrict__ ring) {
  constexpr int CTT = SUB * NSUB;  // steps per handoff boundary
  static_assert(RING_T >= 2 * CTT || RING_T >= T_, "need >=2 chunks of ring slack");
  static_assert((CTT & (CTT - 1)) == 0, "CTT power of 2");
  constexpr int NCH = T_ / CTT;
  const int l    = blockIdx.x >> 1;
  const int gp   = blockIdx.x & 1;
  const int tid  = threadIdx.x;
  const int gg   = tid >> 9;      // block half: 0 or 1
  const int sub  = tid & 511;     // thread id within the half
  const int g    = gp * 2 + gg;   // batch group 0..3
  const int wv   = sub >> 6;      // wave 0..7 within half: gate col-tiles
  const int lane = tid & 63;
  const int q    = lane >> 4;     // quad 0..3
  const int col  = lane & 15;

  __shared__ __align__(16) bf16_t xchunk[2][CTT][16 * LDSW_];  // per-half input
  __shared__ __align__(16) bf16_t hist[2][CTT][16 * LDSW_];    // per-half h history
  __shared__ uint4 wout_lds[5][4][64];                         // L7 out-proj (20 KB)

  // ---- resident weight fragments (bf16, B-layout: lane holds B[k][n], n=col).
  // Weights depend only on (l, wv) — identical for both halves.
  U128 wih[4][4], whh[4][4];  // [gate-class c][k-tile kt]
#pragma unroll
  for (int c = 0; c < 4; ++c) {
    const int n = wv * 16 + c * 128 + col;
#pragma unroll
    for (int kt = 0; kt < 4; ++kt) {
      U128 a, b;
#pragma unroll
      for (int jj = 0; jj < 8; ++jj) {
        const int k = kt * 32 + q * 8 + jj;
        a.b[jj] = (bf16_t)wih_g[(l * H_ + k) * G4_ + n];
        b.b[jj] = (bf16_t)whh_g[(l * H_ + k) * G4_ + n];
      }
      wih[c][kt] = a;
      whh[c][kt] = b;
    }
  }
  // PIN the fragments (32-bit tied operands; 128-bit aggregates unsupported).
#pragma unroll
  for (int c = 0; c < 4; ++c)
#pragma unroll
    for (int kt = 0; kt < 4; ++kt) {
      asm volatile("" : "+v"(wih[c][kt].u.x), "+v"(wih[c][kt].u.y),
                        "+v"(wih[c][kt].u.z), "+v"(wih[c][kt].u.w));
      asm volatile("" : "+v"(whh[c][kt].u.x), "+v"(whh[c][kt].u.y),
                        "+v"(whh[c][kt].u.z), "+v"(whh[c][kt].u.w));
    }

  float bias[4];
#pragma unroll
  for (int c = 0; c < 4; ++c) {
    const int n = wv * 16 + c * 128 + col;
    bias[c] = bih_g[l * G4_ + n] + bhh_g[l * G4_ + n];
  }
  float bo = 0.f;
  const bool has_out = (l == L_ - 1) && (wv < 5);
  if (has_out) {
    const int n = wv * 16 + col;
    if (gg == 0) {  // one half writes the shared image (covered by prologue barrier)
#pragma unroll
      for (int kt = 0; kt < 4; ++kt) {
        U128 w;
#pragma unroll
        for (int jj = 0; jj < 8; ++jj) {
          const int k = kt * 32 + q * 8 + jj;
          w.b[jj] = (n < OUT_) ? (bf16_t)wout_g[k * OUT_ + n] : (bf16_t)(0.f);
        }
        wout_lds[wv][kt][lane] = w.u;
      }
    }
    if (n < OUT_) bo = bout_g[n];
  }

  int* myprod   = flags + ((l * NG_ + g) << 5);
  int* prevprod = (l > 0) ? flags + (((l - 1) * NG_ + g) << 5) : flags;
  int* mycons   = flags + 1024 + ((l * NG_ + g) << 5);
  int* nextcons = (l < L_ - 1) ? flags + 1024 + (((l + 1) * NG_ + g) << 5) : flags;
  u64* myring  = (l < L_ - 1) ? ring + (size_t)(l * NG_ + g) * RING_T * STEP_U64_ : ring;
  const u64* srcring = (l > 0) ? ring + (size_t)((l - 1) * NG_ + g) * RING_T * STEP_U64_ : ring;

  const int aoff = col * LDSW_ + q * 8;  // A-fragment: m=lane&15, k=q*8+j
  float cst[4] = {0.f, 0.f, 0.f, 0.f};  // c-state: rows m=q*4+r, col j=16*wv+col
  int seen_prod = 0, seen_cons = 0;

  // ---- prologue: zero h_{-1}; acquire chunk 0 (each half its own group) ----
  for (int i = sub; i < 16 * LDSW_; i += 512) hist[gg][CTT - 1][i] = (bf16_t)(0.f);
  if (l == 0) {
    const int m  = sub >> 5;
    const int c4 = (sub & 31) << 2;
#pragma unroll
    for (int tl = 0; tl < CTT; ++tl) {
      const int token = xids[(g * BG_ + m) * T_ + tl];
      const float4 e = *(const float4*)(embed + token * H_ + c4);
      bf16x4 v;
      v[0] = (bf16_t)e.x; v[1] = (bf16_t)e.y; v[2] = (bf16_t)e.z; v[3] = (bf16_t)e.w;
      *(bf16x4*)(&xchunk[gg][tl][m * LDSW_ + c4]) = v;
    }
  } else {
    if (sub == 0) {  // tid 0 and tid 512 poll their own group's producer
      int v;
      do { v = flag_ld(prevprod); } while (v < CTT);
      seen_prod = v;
    }
    __syncthreads();
    const int idx = sub >> 2;
    if (idx < CTT * 16) {
      const int tl = idx >> 4, m = idx & 15, seg = sub & 3;
      const u64* src = srcring + (size_t)(tl & (RING_T - 1)) * STEP_U64_ + m * 32 + seg * 8;
      u64* dst = (u64*)(&xchunk[gg][tl][m * LDSW_ + seg * 32]);
#pragma unroll
      for (int j = 0; j < 8; ++j) dst[j] = ring_ld(src + j);
    }
  }
  __syncthreads();  // hist zeroed + xchunk(0) ready + wout_lds ready

#pragma unroll 1
  for (int ch = 0; ch < NCH; ++ch) {
    const int tc0 = ch * CTT;

#pragma unroll
    for (int subc = 0; subc < NSUB; ++subc) {
      const int t0 = tc0 + subc * SUB;

      // ===== phase 1: dense x-half, gx[tl][c] = bias[c] + x_tl @ W_ih =====
      f32x4 gx[SUB][4];
#pragma unroll
      for (int tl = 0; tl < SUB; ++tl) {
        const int st = subc * SUB + tl;
        bf16x8 xa[4];
#pragma unroll
        for (int kt = 0; kt < 4; ++kt)
          xa[kt] = *(const bf16x8*)(&xchunk[gg][st][aoff + kt * 32]);
#pragma unroll
        for (int c = 0; c < 4; ++c) {
          f32x4 a = (f32x4){bias[c], bias[c], bias[c], bias[c]};
#pragma unroll
          for (int kt = 0; kt < 4; ++kt)
            a = __builtin_amdgcn_mfma_f32_16x16x32_bf16(xa[kt], wih[c][kt].b, a, 0, 0, 0);
          gx[tl][c] = a;
        }
      }

      // ===== phase 2: SUB recurrent steps; raw lgkm-only barrier each =====
#pragma unroll
      for (int tl = 0; tl < SUB; ++tl) {
        const int st = subc * SUB + tl;
        bf16x8 ha[4];
#pragma unroll
        for (int kt = 0; kt < 4; ++kt)
          ha[kt] = *(const bf16x8*)(&hist[gg][(st + CTT - 1) & (CTT - 1)][aoff + kt * 32]);
#pragma unroll
        for (int c = 0; c < 4; ++c)
#pragma unroll
          for (int kt = 0; kt < 4; ++kt)
            gx[tl][c] = __builtin_amdgcn_mfma_f32_16x16x32_bf16(ha[kt], whh[c][kt].b, gx[tl][c], 0, 0, 0);

        float hv[4];
        bf16_t hb[4];
#pragma unroll
        for (int r = 0; r < 4; ++r) {
          const float iv = sigm(gx[tl][0][r]);
          const float fv = sigm(gx[tl][1][r]);
          const float gv = tanh_fast(gx[tl][2][r]);
          const float ov = sigm(gx[tl][3][r]);
          const float cv = fv * cst[r] + iv * gv;
          cst[r] = cv;
          const float h = ov * tanh_fast(cv);
          hv[r] = h;
          hb[r] = (bf16_t)h;
        }
        {
          const int jc = wv * 16 + col;
#pragma unroll
          for (int r = 0; r < 4; ++r)
            hist[gg][st][(q * 4 + r) * LDSW_ + jc] = hb[r];
        }
        if (t0 + tl == T_ - 1) {  // final hT / cT (fire-and-forget VMEM)
          const int jc = wv * 16 + col;
#pragma unroll
          for (int r = 0; r < 4; ++r) {
            const int b = g * BG_ + q * 4 + r;
            out[HT_OFF_ + (l * B_ + b) * H_ + jc] = hv[r];
            out[CT_OFF_ + (l * B_ + b) * H_ + jc] = cst[r];
          }
        }
        STEP_BAR();  // hist[gg][st] published; sc1 stores stay in flight

        if (l < L_ - 1) {  // per-step fire-and-forget ring store of hist[gg][st]
          const u64 val = *(const u64*)(&hist[gg][st][(sub >> 5) * LDSW_ + ((sub & 31) << 2)]);
          ring_st(&myring[(size_t)((tc0 + st) & (RING_T - 1)) * STEP_U64_ + sub], val);
        }
      }
    }

    // ===== L7: batched out-projection from hist (whole super-chunk) =====
    if (has_out) {
      const int n = wv * 16 + col;
#pragma unroll
      for (int st = 0; st < CTT; ++st) {
        f32x4 oacc = (f32x4){0.f, 0.f, 0.f, 0.f};
#pragma unroll
        for (int kt = 0; kt < 4; ++kt) {
          U128 w;
          w.u = wout_lds[wv][kt][lane];
          const bf16x8 a = *(const bf16x8*)(&hist[gg][st][col * LDSW_ + kt * 32 + q * 8]);
          oacc = __builtin_amdgcn_mfma_f32_16x16x32_bf16(a, w.b, oacc, 0, 0, 0);
        }
        if (n < OUT_) {
#pragma unroll
          for (int r = 0; r < 4; ++r) {
            const int b = g * BG_ + q * 4 + r;
            out[(b * T_ + (tc0 + st)) * OUT_ + n] = oacc[r] + bo;
          }
        }
      }
    }

    // ===== boundary: poll + single drain + publish + acquire =====
    if (ch + 1 < NCH) {
      if (sub == 0) {  // one poller per half, each for its own group
        if (RING_T < T_ && l > 0) flag_st(mycons, tc0 + CTT);  // BEFORE polls
        if (l > 0) {
          const int target = tc0 + 2 * CTT;
          if (seen_prod < target) {
            int v;
            do { v = flag_ld(prevprod); } while (v < target);
            seen_prod = v;
          }
        }
        if (RING_T < T_ && l < L_ - 1 && tc0 + 2 * CTT > RING_T) {
          const int need = tc0 + 2 * CTT - RING_T;
          if (seen_cons < need) {
            int v;
            do { v = flag_ld(nextcons); } while (v < need);
            seen_cons = v;
          }
        }
      }
      __syncthreads();  // drains the chunk's per-step ring stores; gates polls
      if (l < L_ - 1 && sub == 0) {
        flag_st(myprod, tc0 + CTT);  // all ring stores at coherence point
      }
      if (l == 0) {
        const int m  = sub >> 5;
        const int c4 = (sub & 31) << 2;
#pragma unroll
        for (int tl = 0; tl < CTT; ++tl) {
          const int token = xids[(g * BG_ + m) * T_ + tc0 + CTT + tl];
          const float4 e = *(const float4*)(embed + token * H_ + c4);
          bf16x4 v;
          v[0] = (bf16_t)e.x; v[1] = (bf16_t)e.y; v[2] = (bf16_t)e.z; v[3] = (bf16_t)e.w;
          *(bf16x4*)(&xchunk[gg][tl][m * LDSW_ + c4]) = v;
        }
      } else {
        const int idx = sub >> 2;
        if (idx < CTT * 16) {
          const int tl = idx >> 4, m = idx & 15, seg = sub & 3;
          const u64* src = srcring + (size_t)((tc0 + CTT + tl) & (RING_T - 1)) * STEP_U64_ + m * 32 + seg * 8;
          u64* dst = (u64*)(&xchunk[gg][tl][m * LDSW_ + seg * 32]);
#pragma unroll
          for (int j = 0; j < 8; ++j) dst[j] = ring_ld(src + j);
        }
      }
      __syncthreads();  // xchunk(ch+1) ready
    } else if (l < L_ - 1) {
      // final chunk: stores already issued per-step; drain, publish T_
      __syncthreads();
      if (sub == 0) {
        flag_st(myprod, T_);
      }
    }
  }
}

extern "C" void kernel_launch(void* const* d_in, const int* in_sizes, int n_in,
                              void* d_out, int out_size, void* d_ws, size_t ws_size,
                              hipStream_t stream) {
  (void)in_sizes; (void)n_in; (void)out_size;
  const int*   x     = (const int*)d_in[0];
  const float* embed = (const float*)d_in[1];
  const float* w_ih  = (const float*)d_in[2];
  const float* b_ih  = (const float*)d_in[3];
  const float* w_hh  = (const float*)d_in[4];
  const float* b_hh  = (const float*)d_in[5];
  const float* w_out = (const float*)d_in[6];
  const float* b_out = (const float*)d_in[7];
  float* out = (float*)d_out;

  int* flags = (int*)d_ws;                     // 8 KB: prod@0, cons@4KB
  u64* ring  = (u64*)((char*)d_ws + 8192);

  hipLaunchKernelGGL(zero_flags, dim3(2), dim3(1024), 0, stream, flags);

  auto need = [&](int ring_t) { return (size_t)8192 + (size_t)28 * ring_t * 4096; };

  if (ws_size >= need(512)) {        // 57 MB: full history, no back-pressure
    hipLaunchKernelGGL((lstm_pipe<4, 2, 512>), dim3(L_ * 2), dim3(1024), 0, stream,
                       x, embed, w_ih, b_ih, w_hh, b_hh, w_out, b_out, out, flags, ring);
  } else if (ws_size >= need(16)) {  // 1.8 MB
    hipLaunchKernelGGL((lstm_pipe<4, 2, 16>), dim3(L_ * 2), dim3(1024), 0, stream,
                       x, embed, w_ih, b_ih, w_hh, b_hh, w_out, b_out, out, flags, ring);
  } else if (ws_size >= need(8)) {   // 0.92 MB
    hipLaunchKernelGGL((lstm_pipe<4, 1, 8>), dim3(L_ * 2), dim3(1024), 0, stream,
                       x, embed, w_ih, b_ih, w_hh, b_hh, w_out, b_out, out, flags, ring);
  } else {                           // 0.47 MB worst case
    hipLaunchKernelGGL((lstm_pipe<2, 1, 4>), dim3(L_ * 2), dim3(1024), 0, stream,
                       x, embed, w_ih, b_ih, w_hh, b_hh, w_out, b_out, out, flags, ring);
  }
}

// Round 13
// 5133.927 us; speedup vs baseline: 1.0008x; 1.0008x over previous
//
#include <hip/hip_runtime.h>
#include <hip/hip_bf16.h>

// DeepLSTM on MI355X — v23: v22 with the register budget pinned to the
// 4-wave/SIMD operating point.
//
// v22 post-mortem (5110us): CONFOUNDED, not refuted. VGPR_Count=64 and
// WRITE_SIZE 68->87GB (+19GB scratch spills): with 1024-thread blocks the
// allocator targeted 8 waves/SIMD (512/8=64 VGPR), ignoring that 159KB LDS
// already caps us at 1 block/CU. At 64 VGPR, gx[4][4] alone (64 f32)
// spills. The occupancy/bubble hypothesis never ran.
// Physical budget is fine: 4 waves/SIMD x 128 VGPR = 512 = full file, and
// 128 is what this code has chosen at every cap >=128 all session.
//
// v23 change: amdgpu_waves_per_eu(4,4) pins exactly 4 waves/EU -> VGPR cap
// 128. Everything else byte-identical to v22.
// Verification bits: VGPR 64->128, WRITE_SIZE back to ~68GB.
// Success: ~700-760us. Failure A (serial-bound): ~950-1050 -> revert to
// v21, declare floor. Failure B (VGPR still 64): attribute ignored, revert.
//
// Grid: 16 blocks x 1024 threads; block (l,gp) = layer l, group pair gp;
// half gg = tid>>9 handles group g = gp*2+gg (16 rows).
// ws: [0,8KB) flags (prod@0, cons@4KB, 128B stride); [8KB,...) ring
//     [pair][RING_T][16][128] bf16.

#define T_ 512
#define L_ 8
#define H_ 128
#define G4_ 512
#define OUT_ 65
#define B_ 64
#define NG_ 4
#define BG_ 16
#define LDSW_ 136                          // padded LDS row stride (bf16)
#define HT_OFF_ (B_ * T_ * OUT_)           // 2129920
#define CT_OFF_ (HT_OFF_ + L_ * B_ * H_)   // 2195456
#define STEP_U64_ 512                      // one step's h-tile: 16x128 bf16 = 4KB

typedef __bf16 bf16_t;
typedef bf16_t bf16x8 __attribute__((ext_vector_type(8)));
typedef bf16_t bf16x4 __attribute__((ext_vector_type(4)));
typedef float f32x4 __attribute__((ext_vector_type(4)));
typedef unsigned long long u64;

union U128 { uint4 u; bf16x8 b; u64 d[2]; };

__device__ __forceinline__ float rcpf(float x) { return __builtin_amdgcn_rcpf(x); }
__device__ __forceinline__ float sigm(float x) { return rcpf(1.f + __expf(-x)); }
__device__ __forceinline__ float tanh_fast(float x) {
  const float e = __expf(-2.f * fabsf(x));
  const float r = 2.f * rcpf(1.f + e) - 1.f;
  return copysignf(r, x);
}
__device__ __forceinline__ int flag_ld(int* p) {
  return __hip_atomic_load(p, __ATOMIC_RELAXED, __HIP_MEMORY_SCOPE_AGENT);
}
__device__ __forceinline__ void flag_st(int* p, int v) {
  __hip_atomic_store(p, v, __ATOMIC_RELAXED, __HIP_MEMORY_SCOPE_AGENT);
}
__device__ __forceinline__ u64 ring_ld(const u64* p) {
  return __hip_atomic_load(const_cast<u64*>(p), __ATOMIC_RELAXED, __HIP_MEMORY_SCOPE_AGENT);
}
__device__ __forceinline__ void ring_st(u64* p, u64 v) {
  __hip_atomic_store(p, v, __ATOMIC_RELAXED, __HIP_MEMORY_SCOPE_AGENT);
}

// Raw step barrier: order LDS (hist) writes only; leave sc1 ring stores in
// flight across the barrier. sched_barrier(0) per guide rule #18.
#define STEP_BAR()                                                    \
  do {                                                                \
    asm volatile("s_waitcnt lgkmcnt(0)" ::: "memory");                \
    __builtin_amdgcn_sched_barrier(0);                                \
    __builtin_amdgcn_s_barrier();                                     \
  } while (0)

__global__ void zero_flags(int* flags) { flags[blockIdx.x * 1024 + threadIdx.x] = 0; }

template <int SUB, int NSUB, int RING_T>
__global__
__attribute__((amdgpu_flat_work_group_size(1024, 1024), amdgpu_waves_per_eu(4, 4)))
void lstm_pipe(const int* __restrict__ xids, const float* __restrict__ embed,
               const float* __restrict__ wih_g, const float* __restrict__ bih_g,
               const float* __restrict__ whh_g, const float* __restrict__ bhh_g,
               const float* __restrict__ wout_g, const float* __restrict__ bout_g,
               float* __restrict__ out, int* __restrict__ flags,
               u64* __restrict__ ring) {
  constexpr int CTT = SUB * NSUB;  // steps per handoff boundary
  static_assert(RING_T >= 2 * CTT || RING_T >= T_, "need >=2 chunks of ring slack");
  static_assert((CTT & (CTT - 1)) == 0, "CTT power of 2");
  constexpr int NCH = T_ / CTT;
  const int l    = blockIdx.x >> 1;
  const int gp   = blockIdx.x & 1;
  const int tid  = threadIdx.x;
  const int gg   = tid >> 9;      // block half: 0 or 1
  const int sub  = tid & 511;     // thread id within the half
  const int g    = gp * 2 + gg;   // batch group 0..3
  const int wv   = sub >> 6;      // wave 0..7 within half: gate col-tiles
  const int lane = tid & 63;
  const int q    = lane >> 4;     // quad 0..3
  const int col  = lane & 15;

  __shared__ __align__(16) bf16_t xchunk[2][CTT][16 * LDSW_];  // per-half input
  __shared__ __align__(16) bf16_t hist[2][CTT][16 * LDSW_];    // per-half h history
  __shared__ uint4 wout_lds[5][4][64];                         // L7 out-proj (20 KB)

  // ---- resident weight fragments (bf16, B-layout: lane holds B[k][n], n=col).
  // Weights depend only on (l, wv) — identical for both halves.
  U128 wih[4][4], whh[4][4];  // [gate-class c][k-tile kt]
#pragma unroll
  for (int c = 0; c < 4; ++c) {
    const int n = wv * 16 + c * 128 + col;
#pragma unroll
    for (int kt = 0; kt < 4; ++kt) {
      U128 a, b;
#pragma unroll
      for (int jj = 0; jj < 8; ++jj) {
        const int k = kt * 32 + q * 8 + jj;
        a.b[jj] = (bf16_t)wih_g[(l * H_ + k) * G4_ + n];
        b.b[jj] = (bf16_t)whh_g[(l * H_ + k) * G4_ + n];
      }
      wih[c][kt] = a;
      whh[c][kt] = b;
    }
  }
  // PIN the fragments (32-bit tied operands; 128-bit aggregates unsupported).
#pragma unroll
  for (int c = 0; c < 4; ++c)
#pragma unroll
    for (int kt = 0; kt < 4; ++kt) {
      asm volatile("" : "+v"(wih[c][kt].u.x), "+v"(wih[c][kt].u.y),
                        "+v"(wih[c][kt].u.z), "+v"(wih[c][kt].u.w));
      asm volatile("" : "+v"(whh[c][kt].u.x), "+v"(whh[c][kt].u.y),
                        "+v"(whh[c][kt].u.z), "+v"(whh[c][kt].u.w));
    }

  float bias[4];
#pragma unroll
  for (int c = 0; c < 4; ++c) {
    const int n = wv * 16 + c * 128 + col;
    bias[c] = bih_g[l * G4_ + n] + bhh_g[l * G4_ + n];
  }
  float bo = 0.f;
  const bool has_out = (l == L_ - 1) && (wv < 5);
  if (has_out) {
    const int n = wv * 16 + col;
    if (gg == 0) {  // one half writes the shared image (covered by prologue barrier)
#pragma unroll
      for (int kt = 0; kt < 4; ++kt) {
        U128 w;
#pragma unroll
        for (int jj = 0; jj < 8; ++jj) {
          const int k = kt * 32 + q * 8 + jj;
          w.b[jj] = (n < OUT_) ? (bf16_t)wout_g[k * OUT_ + n] : (bf16_t)(0.f);
        }
        wout_lds[wv][kt][lane] = w.u;
      }
    }
    if (n < OUT_) bo = bout_g[n];
  }

  int* myprod   = flags + ((l * NG_ + g) << 5);
  int* prevprod = (l > 0) ? flags + (((l - 1) * NG_ + g) << 5) : flags;
  int* mycons   = flags + 1024 + ((l * NG_ + g) << 5);
  int* nextcons = (l < L_ - 1) ? flags + 1024 + (((l + 1) * NG_ + g) << 5) : flags;
  u64* myring  = (l < L_ - 1) ? ring + (size_t)(l * NG_ + g) * RING_T * STEP_U64_ : ring;
  const u64* srcring = (l > 0) ? ring + (size_t)((l - 1) * NG_ + g) * RING_T * STEP_U64_ : ring;

  const int aoff = col * LDSW_ + q * 8;  // A-fragment: m=lane&15, k=q*8+j
  float cst[4] = {0.f, 0.f, 0.f, 0.f};  // c-state: rows m=q*4+r, col j=16*wv+col
  int seen_prod = 0, seen_cons = 0;

  // ---- prologue: zero h_{-1}; acquire chunk 0 (each half its own group) ----
  for (int i = sub; i < 16 * LDSW_; i += 512) hist[gg][CTT - 1][i] = (bf16_t)(0.f);
  if (l == 0) {
    const int m  = sub >> 5;
    const int c4 = (sub & 31) << 2;
#pragma unroll
    for (int tl = 0; tl < CTT; ++tl) {
      const int token = xids[(g * BG_ + m) * T_ + tl];
      const float4 e = *(const float4*)(embed + token * H_ + c4);
      bf16x4 v;
      v[0] = (bf16_t)e.x; v[1] = (bf16_t)e.y; v[2] = (bf16_t)e.z; v[3] = (bf16_t)e.w;
      *(bf16x4*)(&xchunk[gg][tl][m * LDSW_ + c4]) = v;
    }
  } else {
    if (sub == 0) {  // tid 0 and tid 512 poll their own group's producer
      int v;
      do { v = flag_ld(prevprod); } while (v < CTT);
      seen_prod = v;
    }
    __syncthreads();
    const int idx = sub >> 2;
    if (idx < CTT * 16) {
      const int tl = idx >> 4, m = idx & 15, seg = sub & 3;
      const u64* src = srcring + (size_t)(tl & (RING_T - 1)) * STEP_U64_ + m * 32 + seg * 8;
      u64* dst = (u64*)(&xchunk[gg][tl][m * LDSW_ + seg * 32]);
#pragma unroll
      for (int j = 0; j < 8; ++j) dst[j] = ring_ld(src + j);
    }
  }
  __syncthreads();  // hist zeroed + xchunk(0) ready + wout_lds ready

#pragma unroll 1
  for (int ch = 0; ch < NCH; ++ch) {
    const int tc0 = ch * CTT;

#pragma unroll
    for (int subc = 0; subc < NSUB; ++subc) {
      const int t0 = tc0 + subc * SUB;

      // ===== phase 1: dense x-half, gx[tl][c] = bias[c] + x_tl @ W_ih =====
      f32x4 gx[SUB][4];
#pragma unroll
      for (int tl = 0; tl < SUB; ++tl) {
        const int st = subc * SUB + tl;
        bf16x8 xa[4];
#pragma unroll
        for (int kt = 0; kt < 4; ++kt)
          xa[kt] = *(const bf16x8*)(&xchunk[gg][st][aoff + kt * 32]);
#pragma unroll
        for (int c = 0; c < 4; ++c) {
          f32x4 a = (f32x4){bias[c], bias[c], bias[c], bias[c]};
#pragma unroll
          for (int kt = 0; kt < 4; ++kt)
            a = __builtin_amdgcn_mfma_f32_16x16x32_bf16(xa[kt], wih[c][kt].b, a, 0, 0, 0);
          gx[tl][c] = a;
        }
      }

      // ===== phase 2: SUB recurrent steps; raw lgkm-only barrier each =====
#pragma unroll
      for (int tl = 0; tl < SUB; ++tl) {
        const int st = subc * SUB + tl;
        bf16x8 ha[4];
#pragma unroll
        for (int kt = 0; kt < 4; ++kt)
          ha[kt] = *(const bf16x8*)(&hist[gg][(st + CTT - 1) & (CTT - 1)][aoff + kt * 32]);
#pragma unroll
        for (int c = 0; c < 4; ++c)
#pragma unroll
          for (int kt = 0; kt < 4; ++kt)
            gx[tl][c] = __builtin_amdgcn_mfma_f32_16x16x32_bf16(ha[kt], whh[c][kt].b, gx[tl][c], 0, 0, 0);

        float hv[4];
        bf16_t hb[4];
#pragma unroll
        for (int r = 0; r < 4; ++r) {
          const float iv = sigm(gx[tl][0][r]);
          const float fv = sigm(gx[tl][1][r]);
          const float gv = tanh_fast(gx[tl][2][r]);
          const float ov = sigm(gx[tl][3][r]);
          const float cv = fv * cst[r] + iv * gv;
          cst[r] = cv;
          const float h = ov * tanh_fast(cv);
          hv[r] = h;
          hb[r] = (bf16_t)h;
        }
        {
          const int jc = wv * 16 + col;
#pragma unroll
          for (int r = 0; r < 4; ++r)
            hist[gg][st][(q * 4 + r) * LDSW_ + jc] = hb[r];
        }
        if (t0 + tl == T_ - 1) {  // final hT / cT (fire-and-forget VMEM)
          const int jc = wv * 16 + col;
#pragma unroll
          for (int r = 0; r < 4; ++r) {
            const int b = g * BG_ + q * 4 + r;
            out[HT_OFF_ + (l * B_ + b) * H_ + jc] = hv[r];
            out[CT_OFF_ + (l * B_ + b) * H_ + jc] = cst[r];
          }
        }
        STEP_BAR();  // hist[gg][st] published; sc1 stores stay in flight

        if (l < L_ - 1) {  // per-step fire-and-forget ring store of hist[gg][st]
          const u64 val = *(const u64*)(&hist[gg][st][(sub >> 5) * LDSW_ + ((sub & 31) << 2)]);
          ring_st(&myring[(size_t)((tc0 + st) & (RING_T - 1)) * STEP_U64_ + sub], val);
        }
      }
    }

    // ===== L7: batched out-projection from hist (whole super-chunk) =====
    if (has_out) {
      const int n = wv * 16 + col;
#pragma unroll
      for (int st = 0; st < CTT; ++st) {
        f32x4 oacc = (f32x4){0.f, 0.f, 0.f, 0.f};
#pragma unroll
        for (int kt = 0; kt < 4; ++kt) {
          U128 w;
          w.u = wout_lds[wv][kt][lane];
          const bf16x8 a = *(const bf16x8*)(&hist[gg][st][col * LDSW_ + kt * 32 + q * 8]);
          oacc = __builtin_amdgcn_mfma_f32_16x16x32_bf16(a, w.b, oacc, 0, 0, 0);
        }
        if (n < OUT_) {
#pragma unroll
          for (int r = 0; r < 4; ++r) {
            const int b = g * BG_ + q * 4 + r;
            out[(b * T_ + (tc0 + st)) * OUT_ + n] = oacc[r] + bo;
          }
        }
      }
    }

    // ===== boundary: poll + single drain + publish + acquire =====
    if (ch + 1 < NCH) {
      if (sub == 0) {  // one poller per half, each for its own group
        if (RING_T < T_ && l > 0) flag_st(mycons, tc0 + CTT);  // BEFORE polls
        if (l > 0) {
          const int target = tc0 + 2 * CTT;
          if (seen_prod < target) {
            int v;
            do { v = flag_ld(prevprod); } while (v < target);
            seen_prod = v;
          }
        }
        if (RING_T < T_ && l < L_ - 1 && tc0 + 2 * CTT > RING_T) {
          const int need = tc0 + 2 * CTT - RING_T;
          if (seen_cons < need) {
            int v;
            do { v = flag_ld(nextcons); } while (v < need);
            seen_cons = v;
          }
        }
      }
      __syncthreads();  // drains the chunk's per-step ring stores; gates polls
      if (l < L_ - 1 && sub == 0) {
        flag_st(myprod, tc0 + CTT);  // all ring stores at coherence point
      }
      if (l == 0) {
        const int m  = sub >> 5;
        const int c4 = (sub & 31) << 2;
#pragma unroll
        for (int tl = 0; tl < CTT; ++tl) {
          const int token = xids[(g * BG_ + m) * T_ + tc0 + CTT + tl];
          const float4 e = *(const float4*)(embed + token * H_ + c4);
          bf16x4 v;
          v[0] = (bf16_t)e.x; v[1] = (bf16_t)e.y; v[2] = (bf16_t)e.z; v[3] = (bf16_t)e.w;
          *(bf16x4*)(&xchunk[gg][tl][m * LDSW_ + c4]) = v;
        }
      } else {
        const int idx = sub >> 2;
        if (idx < CTT * 16) {
          const int tl = idx >> 4, m = idx & 15, seg = sub & 3;
          const u64* src = srcring + (size_t)((tc0 + CTT + tl) & (RING_T - 1)) * STEP_U64_ + m * 32 + seg * 8;
          u64* dst = (u64*)(&xchunk[gg][tl][m * LDSW_ + seg * 32]);
#pragma unroll
          for (int j = 0; j < 8; ++j) dst[j] = ring_ld(src + j);
        }
      }
      __syncthreads();  // xchunk(ch+1) ready
    } else if (l < L_ - 1) {
      // final chunk: stores already issued per-step; drain, publish T_
      __syncthreads();
      if (sub == 0) {
        flag_st(myprod, T_);
      }
    }
  }
}

extern "C" void kernel_launch(void* const* d_in, const int* in_sizes, int n_in,
                              void* d_out, int out_size, void* d_ws, size_t ws_size,
                              hipStream_t stream) {
  (void)in_sizes; (void)n_in; (void)out_size;
  const int*   x     = (const int*)d_in[0];
  const float* embed = (const float*)d_in[1];
  const float* w_ih  = (const float*)d_in[2];
  const float* b_ih  = (const float*)d_in[3];
  const float* w_hh  = (const float*)d_in[4];
  const float* b_hh  = (const float*)d_in[5];
  const float* w_out = (const float*)d_in[6];
  const float* b_out = (const float*)d_in[7];
  float* out = (float*)d_out;

  int* flags = (int*)d_ws;                     // 8 KB: prod@0, cons@4KB
  u64* ring  = (u64*)((char*)d_ws + 8192);

  hipLaunchKernelGGL(zero_flags, dim3(2), dim3(1024), 0, stream, flags);

  auto need = [&](int ring_t) { return (size_t)8192 + (size_t)28 * ring_t * 4096; };

  if (ws_size >= need(512)) {        // 57 MB: full history, no back-pressure
    hipLaunchKernelGGL((lstm_pipe<4, 2, 512>), dim3(L_ * 2), dim3(1024), 0, stream,
                       x, embed, w_ih, b_ih, w_hh, b_hh, w_out, b_out, out, flags, ring);
  } else if (ws_size >= need(16)) {  // 1.8 MB
    hipLaunchKernelGGL((lstm_pipe<4, 2, 16>), dim3(L_ * 2), dim3(1024), 0, stream,
                       x, embed, w_ih, b_ih, w_hh, b_hh, w_out, b_out, out, flags, ring);
  } else if (ws_size >= need(8)) {   // 0.92 MB
    hipLaunchKernelGGL((lstm_pipe<4, 1, 8>), dim3(L_ * 2), dim3(1024), 0, stream,
                       x, embed, w_ih, b_ih, w_hh, b_hh, w_out, b_out, out, flags, ring);
  } else {                           // 0.47 MB worst case
    hipLaunchKernelGGL((lstm_pipe<2, 1, 4>), dim3(L_ * 2), dim3(1024), 0, stream,
                       x, embed, w_ih, b_ih, w_hh, b_hh, w_out, b_out, out, flags, ring);
  }
}

// Round 14
// 902.253 us; speedup vs baseline: 5.6949x; 5.6901x over previous
//
#include <hip/hip_runtime.h>
#include <hip/hip_bf16.h>

// DeepLSTM on MI355X — v24: revert to v21 structure + fused-division gate
// math (10 -> 8 trans ops per r-value).
//
// v23 post-mortem: waves_per_eu(4,4) changed nothing (VGPR 64, 5114us =
// v22). Two mechanically distinct attempts at 4 waves/SIMD produced
// identical spilling code -> 1024-thread path dead; occupancy lever closed.
// Reverting to v21 (806us best).
//
// Remaining lever that touches neither memory nor protocol: algebraic
// trans-op reduction. sigma(a)*tanh(b) = (1-eb)/((1+ea)(1+eb)) — ONE rcp
// for the product instead of two. Applied to iv*gv and ov*tanh(cv); fv
// keeps its own rcp. Per r: 5 exp + 3 rcp (was 5+5): -2 trans (-32cy
// quarter-rate issue) +4 VALU (+8cy) => ~ -190cy/SIMD/step (~5%).
// Overflow safety: exp args clamped to <=60 => e <= 1.1e26 (finite, no
// NaN); if the product (1+ea)(1+eb) overflows to inf, rcp -> 0 which
// equals the true sigma~0 limit. Same real-valued function; fp32-rounding
// differences only.
//
// Grid: 32 blocks x 512 threads; block (l,g) = layer l, batch group g (16 rows).
// ws: [0,8KB) flags (prod@0, cons@4KB, 128B stride); [8KB,...) ring
//     [pair][RING_T][16][128] bf16.

#define T_ 512
#define L_ 8
#define H_ 128
#define G4_ 512
#define OUT_ 65
#define B_ 64
#define NG_ 4
#define BG_ 16
#define LDSW_ 136                          // padded LDS row stride (bf16)
#define HT_OFF_ (B_ * T_ * OUT_)           // 2129920
#define CT_OFF_ (HT_OFF_ + L_ * B_ * H_)   // 2195456
#define STEP_U64_ 512                      // one step's h-tile: 16x128 bf16 = 4KB

typedef __bf16 bf16_t;
typedef bf16_t bf16x8 __attribute__((ext_vector_type(8)));
typedef bf16_t bf16x4 __attribute__((ext_vector_type(4)));
typedef float f32x4 __attribute__((ext_vector_type(4)));
typedef unsigned long long u64;

union U128 { uint4 u; bf16x8 b; u64 d[2]; };

__device__ __forceinline__ float rcpf(float x) { return __builtin_amdgcn_rcpf(x); }
__device__ __forceinline__ int flag_ld(int* p) {
  return __hip_atomic_load(p, __ATOMIC_RELAXED, __HIP_MEMORY_SCOPE_AGENT);
}
__device__ __forceinline__ void flag_st(int* p, int v) {
  __hip_atomic_store(p, v, __ATOMIC_RELAXED, __HIP_MEMORY_SCOPE_AGENT);
}
__device__ __forceinline__ u64 ring_ld(const u64* p) {
  return __hip_atomic_load(const_cast<u64*>(p), __ATOMIC_RELAXED, __HIP_MEMORY_SCOPE_AGENT);
}
__device__ __forceinline__ void ring_st(u64* p, u64 v) {
  __hip_atomic_store(p, v, __ATOMIC_RELAXED, __HIP_MEMORY_SCOPE_AGENT);
}

// Raw step barrier: order LDS (hist) writes only; leave sc1 ring stores in
// flight across the barrier. sched_barrier(0) per guide rule #18.
#define STEP_BAR()                                                    \
  do {                                                                \
    asm volatile("s_waitcnt lgkmcnt(0)" ::: "memory");                \
    __builtin_amdgcn_sched_barrier(0);                                \
    __builtin_amdgcn_s_barrier();                                     \
  } while (0)

__global__ void zero_flags(int* flags) { flags[blockIdx.x * 1024 + threadIdx.x] = 0; }

template <int SUB, int NSUB, int RING_T>
__global__ __launch_bounds__(512, 1)
void lstm_pipe(const int* __restrict__ xids, const float* __restrict__ embed,
               const float* __restrict__ wih_g, const float* __restrict__ bih_g,
               const float* __restrict__ whh_g, const float* __restrict__ bhh_g,
               const float* __restrict__ wout_g, const float* __restrict__ bout_g,
               float* __restrict__ out, int* __restrict__ flags,
               u64* __restrict__ ring) {
  constexpr int CTT = SUB * NSUB;  // steps per handoff boundary
  static_assert(RING_T >= 2 * CTT || RING_T >= T_, "need >=2 chunks of ring slack");
  static_assert((CTT & (CTT - 1)) == 0, "CTT power of 2");
  constexpr int NCH = T_ / CTT;
  const int l    = blockIdx.x >> 2;
  const int g    = blockIdx.x & 3;
  const int tid  = threadIdx.x;
  const int wv   = tid >> 6;      // wave 0..7: gate col-tiles {wv, wv+8, wv+16, wv+24}
  const int lane = tid & 63;
  const int q    = lane >> 4;     // quad 0..3
  const int col  = lane & 15;

  __shared__ __align__(16) bf16_t xchunk[CTT][16 * LDSW_];  // chunk input, A-layout
  __shared__ __align__(16) bf16_t hist[CTT][16 * LDSW_];    // circular h history
  __shared__ uint4 wout_lds[5][4][64];                      // L7 out-proj weights (20 KB)

  // ---- resident weight fragments (bf16, B-layout: lane holds B[k][n], n=col) ----
  U128 wih[4][4], whh[4][4];  // [gate-class c][k-tile kt]
#pragma unroll
  for (int c = 0; c < 4; ++c) {
    const int n = wv * 16 + c * 128 + col;
#pragma unroll
    for (int kt = 0; kt < 4; ++kt) {
      U128 a, b;
#pragma unroll
      for (int jj = 0; jj < 8; ++jj) {
        const int k = kt * 32 + q * 8 + jj;
        a.b[jj] = (bf16_t)wih_g[(l * H_ + k) * G4_ + n];
        b.b[jj] = (bf16_t)whh_g[(l * H_ + k) * G4_ + n];
      }
      wih[c][kt] = a;
      whh[c][kt] = b;
    }
  }
  // PIN the fragments: opaque to remat. 32-bit tied operands (128-bit
  // aggregates are unsupported: "tied indirect register inputs").
#pragma unroll
  for (int c = 0; c < 4; ++c)
#pragma unroll
    for (int kt = 0; kt < 4; ++kt) {
      asm volatile("" : "+v"(wih[c][kt].u.x), "+v"(wih[c][kt].u.y),
                        "+v"(wih[c][kt].u.z), "+v"(wih[c][kt].u.w));
      asm volatile("" : "+v"(whh[c][kt].u.x), "+v"(whh[c][kt].u.y),
                        "+v"(whh[c][kt].u.z), "+v"(whh[c][kt].u.w));
    }

  float bias[4];
#pragma unroll
  for (int c = 0; c < 4; ++c) {
    const int n = wv * 16 + c * 128 + col;
    bias[c] = bih_g[l * G4_ + n] + bhh_g[l * G4_ + n];
  }
  float bo = 0.f;
  const bool has_out = (l == L_ - 1) && (wv < 5);
  if (has_out) {
    const int n = wv * 16 + col;
#pragma unroll
    for (int kt = 0; kt < 4; ++kt) {
      U128 w;
#pragma unroll
      for (int jj = 0; jj < 8; ++jj) {
        const int k = kt * 32 + q * 8 + jj;
        w.b[jj] = (n < OUT_) ? (bf16_t)wout_g[k * OUT_ + n] : (bf16_t)(0.f);
      }
      wout_lds[wv][kt][lane] = w.u;  // stash in LDS, not registers
    }
    if (n < OUT_) bo = bout_g[n];
  }

  int* myprod   = flags + ((l * NG_ + g) << 5);
  int* prevprod = (l > 0) ? flags + (((l - 1) * NG_ + g) << 5) : flags;
  int* mycons   = flags + 1024 + ((l * NG_ + g) << 5);
  int* nextcons = (l < L_ - 1) ? flags + 1024 + (((l + 1) * NG_ + g) << 5) : flags;
  u64* myring  = (l < L_ - 1) ? ring + (size_t)(l * NG_ + g) * RING_T * STEP_U64_ : ring;
  const u64* srcring = (l > 0) ? ring + (size_t)((l - 1) * NG_ + g) * RING_T * STEP_U64_ : ring;

  const int aoff = col * LDSW_ + q * 8;  // A-fragment: m=lane&15, k=q*8+j
  float cst[4] = {0.f, 0.f, 0.f, 0.f};  // c-state: rows m=q*4+r, col j=16*wv+col
  int seen_prod = 0, seen_cons = 0;

  // ---- prologue: zero h_{-1} (hist[CTT-1]); acquire chunk 0 ----
  for (int i = tid; i < 16 * LDSW_; i += 512) hist[CTT - 1][i] = (bf16_t)(0.f);
  if (l == 0) {
    const int m  = tid >> 5;
    const int c4 = (tid & 31) << 2;
#pragma unroll
    for (int tl = 0; tl < CTT; ++tl) {
      const int token = xids[(g * BG_ + m) * T_ + tl];
      const float4 e = *(const float4*)(embed + token * H_ + c4);
      bf16x4 v;
      v[0] = (bf16_t)e.x; v[1] = (bf16_t)e.y; v[2] = (bf16_t)e.z; v[3] = (bf16_t)e.w;
      *(bf16x4*)(&xchunk[tl][m * LDSW_ + c4]) = v;
    }
  } else {
    if (tid == 0) {
      int v;
      do { v = flag_ld(prevprod); } while (v < CTT);
      seen_prod = v;
    }
    __syncthreads();
    const int idx = tid >> 2;
    if (idx < CTT * 16) {
      const int tl = idx >> 4, m = idx & 15, seg = tid & 3;
      const u64* src = srcring + (size_t)(tl & (RING_T - 1)) * STEP_U64_ + m * 32 + seg * 8;
      u64* dst = (u64*)(&xchunk[tl][m * LDSW_ + seg * 32]);
#pragma unroll
      for (int j = 0; j < 8; ++j) dst[j] = ring_ld(src + j);
    }
  }
  __syncthreads();  // hist[CTT-1] zeroed + xchunk(0) ready + wout_lds ready

#pragma unroll 1
  for (int ch = 0; ch < NCH; ++ch) {
    const int tc0 = ch * CTT;

#pragma unroll
    for (int subc = 0; subc < NSUB; ++subc) {
      const int t0 = tc0 + subc * SUB;

      // ===== phase 1: dense x-half, gx[tl][c] = bias[c] + x_tl @ W_ih =====
      f32x4 gx[SUB][4];
#pragma unroll
      for (int tl = 0; tl < SUB; ++tl) {
        const int st = subc * SUB + tl;
        bf16x8 xa[4];
#pragma unroll
        for (int kt = 0; kt < 4; ++kt)
          xa[kt] = *(const bf16x8*)(&xchunk[st][aoff + kt * 32]);
#pragma unroll
        for (int c = 0; c < 4; ++c) {
          f32x4 a = (f32x4){bias[c], bias[c], bias[c], bias[c]};
#pragma unroll
          for (int kt = 0; kt < 4; ++kt)
            a = __builtin_amdgcn_mfma_f32_16x16x32_bf16(xa[kt], wih[c][kt].b, a, 0, 0, 0);
          gx[tl][c] = a;
        }
      }

      // ===== phase 2: SUB recurrent steps; raw lgkm-only barrier each =====
#pragma unroll
      for (int tl = 0; tl < SUB; ++tl) {
        const int st = subc * SUB + tl;
        bf16x8 ha[4];
#pragma unroll
        for (int kt = 0; kt < 4; ++kt)
          ha[kt] = *(const bf16x8*)(&hist[(st + CTT - 1) & (CTT - 1)][aoff + kt * 32]);
#pragma unroll
        for (int c = 0; c < 4; ++c)
#pragma unroll
          for (int kt = 0; kt < 4; ++kt)
            gx[tl][c] = __builtin_amdgcn_mfma_f32_16x16x32_bf16(ha[kt], whh[c][kt].b, gx[tl][c], 0, 0, 0);

        float hv[4];
        bf16_t hb[4];
#pragma unroll
        for (int r = 0; r < 4; ++r) {
          // Fused-division gate math: 5 exp + 3 rcp (was 5+5).
          //   sigma(a)*tanh(b) = (1-eb) / ((1+ea)(1+eb)),  ea=exp(-a), eb=exp(-2b)
          // exp args clamped to <=60: e finite (<=1.1e26, no NaN); product
          // overflow -> rcp = 0 = true sigma~0 limit.
          const float e0 = __expf(fminf(-gx[tl][0][r], 60.f));          // i-gate
          const float e1 = __expf(fminf(-gx[tl][1][r], 60.f));          // f-gate
          const float e2 = __expf(fminf(-2.f * gx[tl][2][r], 60.f));    // g (tanh)
          const float e3 = __expf(fminf(-gx[tl][3][r], 60.f));          // o-gate
          const float fv   = rcpf(1.f + e1);                            // sigma(g1)
          const float ivgv = (1.f - e2) * rcpf((1.f + e0) * (1.f + e2));
          const float cv = fv * cst[r] + ivgv;
          cst[r] = cv;
          const float ec = __expf(fminf(-2.f * cv, 60.f));
          const float h  = (1.f - ec) * rcpf((1.f + e3) * (1.f + ec));  // ov*tanh(cv)
          hv[r] = h;
          hb[r] = (bf16_t)h;
        }
        {
          const int jc = wv * 16 + col;
#pragma unroll
          for (int r = 0; r < 4; ++r)
            hist[st][(q * 4 + r) * LDSW_ + jc] = hb[r];
        }
        if (t0 + tl == T_ - 1) {  // final hT / cT (fire-and-forget VMEM)
          const int jc = wv * 16 + col;
#pragma unroll
          for (int r = 0; r < 4; ++r) {
            const int b = g * BG_ + q * 4 + r;
            out[HT_OFF_ + (l * B_ + b) * H_ + jc] = hv[r];
            out[CT_OFF_ + (l * B_ + b) * H_ + jc] = cst[r];
          }
        }
        STEP_BAR();  // hist[st] published; sc1 stores stay in flight

        if (l < L_ - 1) {  // per-step fire-and-forget ring store of hist[st]
          const u64 val = *(const u64*)(&hist[st][(tid >> 5) * LDSW_ + ((tid & 31) << 2)]);
          ring_st(&myring[(size_t)((tc0 + st) & (RING_T - 1)) * STEP_U64_ + tid], val);
        }
      }
    }

    // ===== L7: batched out-projection from hist (whole super-chunk) =====
    if (has_out) {
      const int n = wv * 16 + col;
#pragma unroll
      for (int st = 0; st < CTT; ++st) {
        f32x4 oacc = (f32x4){0.f, 0.f, 0.f, 0.f};
#pragma unroll
        for (int kt = 0; kt < 4; ++kt) {
          U128 w;
          w.u = wout_lds[wv][kt][lane];
          const bf16x8 a = *(const bf16x8*)(&hist[st][col * LDSW_ + kt * 32 + q * 8]);
          oacc = __builtin_amdgcn_mfma_f32_16x16x32_bf16(a, w.b, oacc, 0, 0, 0);
        }
        if (n < OUT_) {
#pragma unroll
          for (int r = 0; r < 4; ++r) {
            const int b = g * BG_ + q * 4 + r;
            out[(b * T_ + (tc0 + st)) * OUT_ + n] = oacc[r] + bo;
          }
        }
      }
    }

    // ===== boundary: poll + single drain + publish + acquire =====
    if (ch + 1 < NCH) {
      if (tid == 0) {
        if (RING_T < T_ && l > 0) flag_st(mycons, tc0 + CTT);  // BEFORE polls
        if (l > 0) {
          const int target = tc0 + 2 * CTT;
          if (seen_prod < target) {
            int v;
            do { v = flag_ld(prevprod); } while (v < target);
            seen_prod = v;
          }
        }
        if (RING_T < T_ && l < L_ - 1 && tc0 + 2 * CTT > RING_T) {
          const int need = tc0 + 2 * CTT - RING_T;
          if (seen_cons < need) {
            int v;
            do { v = flag_ld(nextcons); } while (v < need);
            seen_cons = v;
          }
        }
      }
      __syncthreads();  // drains the chunk's per-step ring stores; gates polls
      if (l < L_ - 1 && tid == 0) {
        flag_st(myprod, tc0 + CTT);  // all ring stores at coherence point
      }
      if (l == 0) {
        const int m  = tid >> 5;
        const int c4 = (tid & 31) << 2;
#pragma unroll
        for (int tl = 0; tl < CTT; ++tl) {
          const int token = xids[(g * BG_ + m) * T_ + tc0 + CTT + tl];
          const float4 e = *(const float4*)(embed + token * H_ + c4);
          bf16x4 v;
          v[0] = (bf16_t)e.x; v[1] = (bf16_t)e.y; v[2] = (bf16_t)e.z; v[3] = (bf16_t)e.w;
          *(bf16x4*)(&xchunk[tl][m * LDSW_ + c4]) = v;
        }
      } else {
        const int idx = tid >> 2;
        if (idx < CTT * 16) {
          const int tl = idx >> 4, m = idx & 15, seg = tid & 3;
          const u64* src = srcring + (size_t)((tc0 + CTT + tl) & (RING_T - 1)) * STEP_U64_ + m * 32 + seg * 8;
          u64* dst = (u64*)(&xchunk[tl][m * LDSW_ + seg * 32]);
#pragma unroll
          for (int j = 0; j < 8; ++j) dst[j] = ring_ld(src + j);
        }
      }
      __syncthreads();  // xchunk(ch+1) ready
    } else if (l < L_ - 1) {
      // final chunk: stores already issued per-step; drain, publish T_
      __syncthreads();
      if (tid == 0) {
        flag_st(myprod, T_);
      }
    }
  }
}

extern "C" void kernel_launch(void* const* d_in, const int* in_sizes, int n_in,
                              void* d_out, int out_size, void* d_ws, size_t ws_size,
                              hipStream_t stream) {
  (void)in_sizes; (void)n_in; (void)out_size;
  const int*   x     = (const int*)d_in[0];
  const float* embed = (const float*)d_in[1];
  const float* w_ih  = (const float*)d_in[2];
  const float* b_ih  = (const float*)d_in[3];
  const float* w_hh  = (const float*)d_in[4];
  const float* b_hh  = (const float*)d_in[5];
  const float* w_out = (const float*)d_in[6];
  const float* b_out = (const float*)d_in[7];
  float* out = (float*)d_out;

  int* flags = (int*)d_ws;                     // 8 KB: prod@0, cons@4KB
  u64* ring  = (u64*)((char*)d_ws + 8192);

  hipLaunchKernelGGL(zero_flags, dim3(2), dim3(1024), 0, stream, flags);

  auto need = [&](int ring_t) { return (size_t)8192 + (size_t)28 * ring_t * 4096; };

  if (ws_size >= need(512)) {        // 57 MB: full history, no back-pressure
    hipLaunchKernelGGL((lstm_pipe<4, 2, 512>), dim3(L_ * NG_), dim3(512), 0, stream,
                       x, embed, w_ih, b_ih, w_hh, b_hh, w_out, b_out, out, flags, ring);
  } else if (ws_size >= need(16)) {  // 1.8 MB
    hipLaunchKernelGGL((lstm_pipe<4, 2, 16>), dim3(L_ * NG_), dim3(512), 0, stream,
                       x, embed, w_ih, b_ih, w_hh, b_hh, w_out, b_out, out, flags, ring);
  } else if (ws_size >= need(8)) {   // 0.92 MB
    hipLaunchKernelGGL((lstm_pipe<4, 1, 8>), dim3(L_ * NG_), dim3(512), 0, stream,
                       x, embed, w_ih, b_ih, w_hh, b_hh, w_out, b_out, out, flags, ring);
  } else {                           // 0.47 MB worst case
    hipLaunchKernelGGL((lstm_pipe<2, 1, 4>), dim3(L_ * NG_), dim3(512), 0, stream,
                       x, embed, w_ih, b_ih, w_hh, b_hh, w_out, b_out, out, flags, ring);
  }
}

// Round 15
// 867.055 us; speedup vs baseline: 5.9261x; 1.0406x over previous
//
#include <hip/hip_runtime.h>
#include <hip/hip_bf16.h>

// DeepLSTM on MI355X — v25: restore v21 exactly (best: 869.8us harness /
// 806us steady).
//
// v24 post-mortem: fused-division gate math regressed 4% (839 vs 806) and
// VALUBusy ROSE despite fewer trans ops — fourth failed issue-reduction
// theory (v15 LUT, v16 pins, v19 LDS-weights, v24 algebra). Combined with
// the occupancy failures (v22/v23: allocator spill wall at 64 VGPR) and
// three neutral boundary probes (v13/v20-21 batched/fire-and-forget), the
// evidence closes: the step period is a latency/serialization floor —
// 512 sequential steps x (block-wide h exchange + barrier + dependent
// MFMA/VALU chain) at 2 waves/SIMD. Floor arithmetic: 512 x 1.42us +
// 64 x 1.5us boundaries + ~80us fill ~ 805-830us; v21 sits on it.
// Counters at this floor: HBM 1.6%, MfmaUtil 3.4%, VALUBusy 5.2% — no
// pipe is near its roofline; the bound is the dependency chain itself.
//
// This file is byte-identical to v21.
//
// Grid: 32 blocks x 512 threads; block (l,g) = layer l, batch group g (16 rows).
// ws: [0,8KB) flags (prod@0, cons@4KB, 128B stride); [8KB,...) ring
//     [pair][RING_T][16][128] bf16.

#define T_ 512
#define L_ 8
#define H_ 128
#define G4_ 512
#define OUT_ 65
#define B_ 64
#define NG_ 4
#define BG_ 16
#define LDSW_ 136                          // padded LDS row stride (bf16)
#define HT_OFF_ (B_ * T_ * OUT_)           // 2129920
#define CT_OFF_ (HT_OFF_ + L_ * B_ * H_)   // 2195456
#define STEP_U64_ 512                      // one step's h-tile: 16x128 bf16 = 4KB

typedef __bf16 bf16_t;
typedef bf16_t bf16x8 __attribute__((ext_vector_type(8)));
typedef bf16_t bf16x4 __attribute__((ext_vector_type(4)));
typedef float f32x4 __attribute__((ext_vector_type(4)));
typedef unsigned long long u64;

union U128 { uint4 u; bf16x8 b; u64 d[2]; };

__device__ __forceinline__ float rcpf(float x) { return __builtin_amdgcn_rcpf(x); }
__device__ __forceinline__ float sigm(float x) { return rcpf(1.f + __expf(-x)); }
__device__ __forceinline__ float tanh_fast(float x) {
  const float e = __expf(-2.f * fabsf(x));
  const float r = 2.f * rcpf(1.f + e) - 1.f;
  return copysignf(r, x);
}
__device__ __forceinline__ int flag_ld(int* p) {
  return __hip_atomic_load(p, __ATOMIC_RELAXED, __HIP_MEMORY_SCOPE_AGENT);
}
__device__ __forceinline__ void flag_st(int* p, int v) {
  __hip_atomic_store(p, v, __ATOMIC_RELAXED, __HIP_MEMORY_SCOPE_AGENT);
}
__device__ __forceinline__ u64 ring_ld(const u64* p) {
  return __hip_atomic_load(const_cast<u64*>(p), __ATOMIC_RELAXED, __HIP_MEMORY_SCOPE_AGENT);
}
__device__ __forceinline__ void ring_st(u64* p, u64 v) {
  __hip_atomic_store(p, v, __ATOMIC_RELAXED, __HIP_MEMORY_SCOPE_AGENT);
}

// Raw step barrier: order LDS (hist) writes only; leave sc1 ring stores in
// flight across the barrier. sched_barrier(0) per guide rule #18.
#define STEP_BAR()                                                    \
  do {                                                                \
    asm volatile("s_waitcnt lgkmcnt(0)" ::: "memory");                \
    __builtin_amdgcn_sched_barrier(0);                                \
    __builtin_amdgcn_s_barrier();                                     \
  } while (0)

__global__ void zero_flags(int* flags) { flags[blockIdx.x * 1024 + threadIdx.x] = 0; }

template <int SUB, int NSUB, int RING_T>
__global__ __launch_bounds__(512, 1)
void lstm_pipe(const int* __restrict__ xids, const float* __restrict__ embed,
               const float* __restrict__ wih_g, const float* __restrict__ bih_g,
               const float* __restrict__ whh_g, const float* __restrict__ bhh_g,
               const float* __restrict__ wout_g, const float* __restrict__ bout_g,
               float* __restrict__ out, int* __restrict__ flags,
               u64* __restrict__ ring) {
  constexpr int CTT = SUB * NSUB;  // steps per handoff boundary
  static_assert(RING_T >= 2 * CTT || RING_T >= T_, "need >=2 chunks of ring slack");
  static_assert((CTT & (CTT - 1)) == 0, "CTT power of 2");
  constexpr int NCH = T_ / CTT;
  const int l    = blockIdx.x >> 2;
  const int g    = blockIdx.x & 3;
  const int tid  = threadIdx.x;
  const int wv   = tid >> 6;      // wave 0..7: gate col-tiles {wv, wv+8, wv+16, wv+24}
  const int lane = tid & 63;
  const int q    = lane >> 4;     // quad 0..3
  const int col  = lane & 15;

  __shared__ __align__(16) bf16_t xchunk[CTT][16 * LDSW_];  // chunk input, A-layout
  __shared__ __align__(16) bf16_t hist[CTT][16 * LDSW_];    // circular h history
  __shared__ uint4 wout_lds[5][4][64];                      // L7 out-proj weights (20 KB)

  // ---- resident weight fragments (bf16, B-layout: lane holds B[k][n], n=col) ----
  U128 wih[4][4], whh[4][4];  // [gate-class c][k-tile kt]
#pragma unroll
  for (int c = 0; c < 4; ++c) {
    const int n = wv * 16 + c * 128 + col;
#pragma unroll
    for (int kt = 0; kt < 4; ++kt) {
      U128 a, b;
#pragma unroll
      for (int jj = 0; jj < 8; ++jj) {
        const int k = kt * 32 + q * 8 + jj;
        a.b[jj] = (bf16_t)wih_g[(l * H_ + k) * G4_ + n];
        b.b[jj] = (bf16_t)whh_g[(l * H_ + k) * G4_ + n];
      }
      wih[c][kt] = a;
      whh[c][kt] = b;
    }
  }
  // PIN the fragments: opaque to remat. 32-bit tied operands (128-bit
  // aggregates are unsupported: "tied indirect register inputs").
#pragma unroll
  for (int c = 0; c < 4; ++c)
#pragma unroll
    for (int kt = 0; kt < 4; ++kt) {
      asm volatile("" : "+v"(wih[c][kt].u.x), "+v"(wih[c][kt].u.y),
                        "+v"(wih[c][kt].u.z), "+v"(wih[c][kt].u.w));
      asm volatile("" : "+v"(whh[c][kt].u.x), "+v"(whh[c][kt].u.y),
                        "+v"(whh[c][kt].u.z), "+v"(whh[c][kt].u.w));
    }

  float bias[4];
#pragma unroll
  for (int c = 0; c < 4; ++c) {
    const int n = wv * 16 + c * 128 + col;
    bias[c] = bih_g[l * G4_ + n] + bhh_g[l * G4_ + n];
  }
  float bo = 0.f;
  const bool has_out = (l == L_ - 1) && (wv < 5);
  if (has_out) {
    const int n = wv * 16 + col;
#pragma unroll
    for (int kt = 0; kt < 4; ++kt) {
      U128 w;
#pragma unroll
      for (int jj = 0; jj < 8; ++jj) {
        const int k = kt * 32 + q * 8 + jj;
        w.b[jj] = (n < OUT_) ? (bf16_t)wout_g[k * OUT_ + n] : (bf16_t)(0.f);
      }
      wout_lds[wv][kt][lane] = w.u;  // stash in LDS, not registers
    }
    if (n < OUT_) bo = bout_g[n];
  }

  int* myprod   = flags + ((l * NG_ + g) << 5);
  int* prevprod = (l > 0) ? flags + (((l - 1) * NG_ + g) << 5) : flags;
  int* mycons   = flags + 1024 + ((l * NG_ + g) << 5);
  int* nextcons = (l < L_ - 1) ? flags + 1024 + (((l + 1) * NG_ + g) << 5) : flags;
  u64* myring  = (l < L_ - 1) ? ring + (size_t)(l * NG_ + g) * RING_T * STEP_U64_ : ring;
  const u64* srcring = (l > 0) ? ring + (size_t)((l - 1) * NG_ + g) * RING_T * STEP_U64_ : ring;

  const int aoff = col * LDSW_ + q * 8;  // A-fragment: m=lane&15, k=q*8+j
  float cst[4] = {0.f, 0.f, 0.f, 0.f};  // c-state: rows m=q*4+r, col j=16*wv+col
  int seen_prod = 0, seen_cons = 0;

  // ---- prologue: zero h_{-1} (hist[CTT-1]); acquire chunk 0 ----
  for (int i = tid; i < 16 * LDSW_; i += 512) hist[CTT - 1][i] = (bf16_t)(0.f);
  if (l == 0) {
    const int m  = tid >> 5;
    const int c4 = (tid & 31) << 2;
#pragma unroll
    for (int tl = 0; tl < CTT; ++tl) {
      const int token = xids[(g * BG_ + m) * T_ + tl];
      const float4 e = *(const float4*)(embed + token * H_ + c4);
      bf16x4 v;
      v[0] = (bf16_t)e.x; v[1] = (bf16_t)e.y; v[2] = (bf16_t)e.z; v[3] = (bf16_t)e.w;
      *(bf16x4*)(&xchunk[tl][m * LDSW_ + c4]) = v;
    }
  } else {
    if (tid == 0) {
      int v;
      do { v = flag_ld(prevprod); } while (v < CTT);
      seen_prod = v;
    }
    __syncthreads();
    const int idx = tid >> 2;
    if (idx < CTT * 16) {
      const int tl = idx >> 4, m = idx & 15, seg = tid & 3;
      const u64* src = srcring + (size_t)(tl & (RING_T - 1)) * STEP_U64_ + m * 32 + seg * 8;
      u64* dst = (u64*)(&xchunk[tl][m * LDSW_ + seg * 32]);
#pragma unroll
      for (int j = 0; j < 8; ++j) dst[j] = ring_ld(src + j);
    }
  }
  __syncthreads();  // hist[CTT-1] zeroed + xchunk(0) ready + wout_lds ready

#pragma unroll 1
  for (int ch = 0; ch < NCH; ++ch) {
    const int tc0 = ch * CTT;

#pragma unroll
    for (int subc = 0; subc < NSUB; ++subc) {
      const int t0 = tc0 + subc * SUB;

      // ===== phase 1: dense x-half, gx[tl][c] = bias[c] + x_tl @ W_ih =====
      f32x4 gx[SUB][4];
#pragma unroll
      for (int tl = 0; tl < SUB; ++tl) {
        const int st = subc * SUB + tl;
        bf16x8 xa[4];
#pragma unroll
        for (int kt = 0; kt < 4; ++kt)
          xa[kt] = *(const bf16x8*)(&xchunk[st][aoff + kt * 32]);
#pragma unroll
        for (int c = 0; c < 4; ++c) {
          f32x4 a = (f32x4){bias[c], bias[c], bias[c], bias[c]};
#pragma unroll
          for (int kt = 0; kt < 4; ++kt)
            a = __builtin_amdgcn_mfma_f32_16x16x32_bf16(xa[kt], wih[c][kt].b, a, 0, 0, 0);
          gx[tl][c] = a;
        }
      }

      // ===== phase 2: SUB recurrent steps; raw lgkm-only barrier each =====
#pragma unroll
      for (int tl = 0; tl < SUB; ++tl) {
        const int st = subc * SUB + tl;
        bf16x8 ha[4];
#pragma unroll
        for (int kt = 0; kt < 4; ++kt)
          ha[kt] = *(const bf16x8*)(&hist[(st + CTT - 1) & (CTT - 1)][aoff + kt * 32]);
#pragma unroll
        for (int c = 0; c < 4; ++c)
#pragma unroll
          for (int kt = 0; kt < 4; ++kt)
            gx[tl][c] = __builtin_amdgcn_mfma_f32_16x16x32_bf16(ha[kt], whh[c][kt].b, gx[tl][c], 0, 0, 0);

        float hv[4];
        bf16_t hb[4];
#pragma unroll
        for (int r = 0; r < 4; ++r) {
          const float iv = sigm(gx[tl][0][r]);
          const float fv = sigm(gx[tl][1][r]);
          const float gv = tanh_fast(gx[tl][2][r]);
          const float ov = sigm(gx[tl][3][r]);
          const float cv = fv * cst[r] + iv * gv;
          cst[r] = cv;
          const float h = ov * tanh_fast(cv);
          hv[r] = h;
          hb[r] = (bf16_t)h;
        }
        {
          const int jc = wv * 16 + col;
#pragma unroll
          for (int r = 0; r < 4; ++r)
            hist[st][(q * 4 + r) * LDSW_ + jc] = hb[r];
        }
        if (t0 + tl == T_ - 1) {  // final hT / cT (fire-and-forget VMEM)
          const int jc = wv * 16 + col;
#pragma unroll
          for (int r = 0; r < 4; ++r) {
            const int b = g * BG_ + q * 4 + r;
            out[HT_OFF_ + (l * B_ + b) * H_ + jc] = hv[r];
            out[CT_OFF_ + (l * B_ + b) * H_ + jc] = cst[r];
          }
        }
        STEP_BAR();  // hist[st] published; sc1 stores stay in flight

        if (l < L_ - 1) {  // per-step fire-and-forget ring store of hist[st]
          const u64 val = *(const u64*)(&hist[st][(tid >> 5) * LDSW_ + ((tid & 31) << 2)]);
          ring_st(&myring[(size_t)((tc0 + st) & (RING_T - 1)) * STEP_U64_ + tid], val);
        }
      }
    }

    // ===== L7: batched out-projection from hist (whole super-chunk) =====
    if (has_out) {
      const int n = wv * 16 + col;
#pragma unroll
      for (int st = 0; st < CTT; ++st) {
        f32x4 oacc = (f32x4){0.f, 0.f, 0.f, 0.f};
#pragma unroll
        for (int kt = 0; kt < 4; ++kt) {
          U128 w;
          w.u = wout_lds[wv][kt][lane];
          const bf16x8 a = *(const bf16x8*)(&hist[st][col * LDSW_ + kt * 32 + q * 8]);
          oacc = __builtin_amdgcn_mfma_f32_16x16x32_bf16(a, w.b, oacc, 0, 0, 0);
        }
        if (n < OUT_) {
#pragma unroll
          for (int r = 0; r < 4; ++r) {
            const int b = g * BG_ + q * 4 + r;
            out[(b * T_ + (tc0 + st)) * OUT_ + n] = oacc[r] + bo;
          }
        }
      }
    }

    // ===== boundary: poll + single drain + publish + acquire =====
    if (ch + 1 < NCH) {
      if (tid == 0) {
        if (RING_T < T_ && l > 0) flag_st(mycons, tc0 + CTT);  // BEFORE polls
        if (l > 0) {
          const int target = tc0 + 2 * CTT;
          if (seen_prod < target) {
            int v;
            do { v = flag_ld(prevprod); } while (v < target);
            seen_prod = v;
          }
        }
        if (RING_T < T_ && l < L_ - 1 && tc0 + 2 * CTT > RING_T) {
          const int need = tc0 + 2 * CTT - RING_T;
          if (seen_cons < need) {
            int v;
            do { v = flag_ld(nextcons); } while (v < need);
            seen_cons = v;
          }
        }
      }
      __syncthreads();  // drains the chunk's per-step ring stores; gates polls
      if (l < L_ - 1 && tid == 0) {
        flag_st(myprod, tc0 + CTT);  // all ring stores at coherence point
      }
      if (l == 0) {
        const int m  = tid >> 5;
        const int c4 = (tid & 31) << 2;
#pragma unroll
        for (int tl = 0; tl < CTT; ++tl) {
          const int token = xids[(g * BG_ + m) * T_ + tc0 + CTT + tl];
          const float4 e = *(const float4*)(embed + token * H_ + c4);
          bf16x4 v;
          v[0] = (bf16_t)e.x; v[1] = (bf16_t)e.y; v[2] = (bf16_t)e.z; v[3] = (bf16_t)e.w;
          *(bf16x4*)(&xchunk[tl][m * LDSW_ + c4]) = v;
        }
      } else {
        const int idx = tid >> 2;
        if (idx < CTT * 16) {
          const int tl = idx >> 4, m = idx & 15, seg = tid & 3;
          const u64* src = srcring + (size_t)((tc0 + CTT + tl) & (RING_T - 1)) * STEP_U64_ + m * 32 + seg * 8;
          u64* dst = (u64*)(&xchunk[tl][m * LDSW_ + seg * 32]);
#pragma unroll
          for (int j = 0; j < 8; ++j) dst[j] = ring_ld(src + j);
        }
      }
      __syncthreads();  // xchunk(ch+1) ready
    } else if (l < L_ - 1) {
      // final chunk: stores already issued per-step; drain, publish T_
      __syncthreads();
      if (tid == 0) {
        flag_st(myprod, T_);
      }
    }
  }
}

extern "C" void kernel_launch(void* const* d_in, const int* in_sizes, int n_in,
                              void* d_out, int out_size, void* d_ws, size_t ws_size,
                              hipStream_t stream) {
  (void)in_sizes; (void)n_in; (void)out_size;
  const int*   x     = (const int*)d_in[0];
  const float* embed = (const float*)d_in[1];
  const float* w_ih  = (const float*)d_in[2];
  const float* b_ih  = (const float*)d_in[3];
  const float* w_hh  = (const float*)d_in[4];
  const float* b_hh  = (const float*)d_in[5];
  const float* w_out = (const float*)d_in[6];
  const float* b_out = (const float*)d_in[7];
  float* out = (float*)d_out;

  int* flags = (int*)d_ws;                     // 8 KB: prod@0, cons@4KB
  u64* ring  = (u64*)((char*)d_ws + 8192);

  hipLaunchKernelGGL(zero_flags, dim3(2), dim3(1024), 0, stream, flags);

  auto need = [&](int ring_t) { return (size_t)8192 + (size_t)28 * ring_t * 4096; };

  if (ws_size >= need(512)) {        // 57 MB: full history, no back-pressure
    hipLaunchKernelGGL((lstm_pipe<4, 2, 512>), dim3(L_ * NG_), dim3(512), 0, stream,
                       x, embed, w_ih, b_ih, w_hh, b_hh, w_out, b_out, out, flags, ring);
  } else if (ws_size >= need(16)) {  // 1.8 MB
    hipLaunchKernelGGL((lstm_pipe<4, 2, 16>), dim3(L_ * NG_), dim3(512), 0, stream,
                       x, embed, w_ih, b_ih, w_hh, b_hh, w_out, b_out, out, flags, ring);
  } else if (ws_size >= need(8)) {   // 0.92 MB
    hipLaunchKernelGGL((lstm_pipe<4, 1, 8>), dim3(L_ * NG_), dim3(512), 0, stream,
                       x, embed, w_ih, b_ih, w_hh, b_hh, w_out, b_out, out, flags, ring);
  } else {                           // 0.47 MB worst case
    hipLaunchKernelGGL((lstm_pipe<2, 1, 4>), dim3(L_ * NG_), dim3(512), 0, stream,
                       x, embed, w_ih, b_ih, w_hh, b_hh, w_out, b_out, out, flags, ring);
  }
}